// Round 4
// baseline (191.250 us; speedup 1.0000x reference)
//
#include <hip/hip_runtime.h>
#include <hip/hip_cooperative_groups.h>
#include <math.h>

#define NB 16
#define NC 256
#define NHW 1024
#define NE 512
#define NDQ 4
#define NLQ 4
#define NQB 6
#define QDIM 64
#define PIX 32
#define HSS 264    // hs row stride in bf16 elems (2-way bank conflict = free)
#define XSS 36     // xs2 row stride (floats): 32->36 kills 16-way P4 read conflict

typedef float v2f __attribute__((ext_vector_type(2)));
typedef float f32x4 __attribute__((ext_vector_type(4)));
typedef short bf16x8 __attribute__((ext_vector_type(8)));   // 8 bf16 (4 VGPRs)

__device__ __forceinline__ short f2bf(float v) {   // RNE f32 -> bf16 bits
    unsigned u = __builtin_bit_cast(unsigned, v);
    u += 0x7FFFu + ((u >> 16) & 1u);
    return (short)(u >> 16);
}

// ======== constexpr circuit algebra (CNOT ring is GF(2)-linear) ========
constexpr int fwd1(int i) {
    int r = i;
    for (int c = 0; c < NQB; ++c) {
        int t = (c + 1) % NQB;
        if ((r >> (NQB - 1 - c)) & 1) r ^= 1 << (NQB - 1 - t);
    }
    return r;
}
constexpr int fwdl(int s, int l) { for (int i = 0; i < l; ++i) s = fwd1(s); return s; }
constexpr int parity6(int x) { x ^= x >> 4; x ^= x >> 2; x ^= x >> 1; return x & 1; }

// Verified by R8-R11 passing runs.
struct GateTab { int M[NLQ][NQB]; int V[NLQ][NQB]; int W[NDQ]; };
constexpr GateTab make_tab() {
    GateTab g{};
    for (int l = 0; l < NLQ; ++l)
        for (int q = 0; q < NQB; ++q) {
            int m = 1 << (NQB - 1 - q);
            for (int x = 0; x < QDIM; ++x) if (fwdl(x, l) == m) { g.M[l][q] = x; break; }
            int V = 0;
            for (int t = 0; t < NQB; ++t) V |= ((fwdl(1 << t, l) >> (NQB - 1 - q)) & 1) << t;
            g.V[l][q] = V;
        }
    for (int d = 0; d < NDQ; ++d) {
        int W = 0;
        for (int t = 0; t < NQB; ++t) W |= ((fwdl(1 << t, NLQ) >> (NQB - 1 - d)) & 1) << t;
        g.W[d] = W;
    }
    return g;
}
constexpr GateTab GT = make_tab();

// Shared layout for the main tile work: 16896 + 36864*? ... total 58368 B (57 KB); x2 blocks = 114 KB <= 160 OK
struct Smem {
    short hs[PIX * HSS];     // normalized h bf16 [px][c], 16.9 KB
    float xs2[NC * XSS];     // raw x stash [c][px] padded, 36.9 KB
    float as_[PIX * 36];     // ang/meas [px][o] (aliased as es[512] in phase A), 4.6 KB
};

// ---------- phase B body (shared by fused and fallback kernels) ----------
__device__ __forceinline__ void phaseB(Smem& sm, const float4* xr, int b, int pbase, int t,
                                       const float* __restrict__ scs,
                                       const float* __restrict__ shs,
                                       const float* __restrict__ b_in,
                                       const float* __restrict__ A,
                                       const short* __restrict__ w_in_bf,
                                       const short* __restrict__ w_out_bf,
                                       const float* __restrict__ b_out,
                                       float* __restrict__ out) {
    short* hs  = sm.hs;
    float* xs2 = sm.xs2;
    float* as_ = sm.as_;

    int lane = t & 63, wv = t >> 6;
    int c0 = t >> 3, p4 = (t & 7) * 4;
    int nn = lane & 15, quad = lane >> 4;
    int mt = wv >> 1, nt = wv & 1;       // P2 tile: px-half, o-half

    // ---- all waves: preload own P2 B-fragments (w_in bf16) ----
    bf16x8 bfrag[8];
    {
        int o = nt * 16 + nn;
        #pragma unroll
        for (int s = 0; s < 8; ++s)
            bfrag[s] = *(const bf16x8*)(w_in_bf + o * NC + s * 32 + quad * 8);
    }

    // ---- all threads: preload style table ----
    float Ar[24];
    {
        int g = t >> 5;
        const float4* Ab4 = (const float4*)(A + b * 192 + g * 24);
        #pragma unroll
        for (int j = 0; j < 6; ++j) {
            float4 a4 = Ab4[j];
            Ar[4*j] = a4.x; Ar[4*j+1] = a4.y; Ar[4*j+2] = a4.z; Ar[4*j+3] = a4.w;
        }
    }

    // ---- P1: normalize (precomputed scale/shift) -> hs bf16 [px][c] ----
    #pragma unroll
    for (int k = 0; k < 8; ++k) {
        int c = c0 + 32 * k;
        float sc = scs[b * NC + c];
        float sh = shs[b * NC + c];
        float4 v = xr[k];
        hs[(p4 + 0) * HSS + c] = f2bf(fmaf(v.x, sc, sh));
        hs[(p4 + 1) * HSS + c] = f2bf(fmaf(v.y, sc, sh));
        hs[(p4 + 2) * HSS + c] = f2bf(fmaf(v.z, sc, sh));
        hs[(p4 + 3) * HSS + c] = f2bf(fmaf(v.w, sc, sh));
    }
    __syncthreads();

    // ---- P2 (all waves): ang = h @ w_in^T via MFMA 16x16x32, one tile/wave ----
    {
        f32x4 acc = {0.f, 0.f, 0.f, 0.f};
        #pragma unroll
        for (int s = 0; s < 8; ++s) {
            bf16x8 afr = *(const bf16x8*)(hs + (mt * 16 + nn) * HSS + s * 32 + quad * 8);
            acc = __builtin_amdgcn_mfma_f32_16x16x32_bf16(afr, bfrag[s], acc, 0, 0, 0);
        }
        int o = nt * 16 + nn;
        float bi = b_in[o];
        #pragma unroll
        for (int r = 0; r < 4; ++r)
            as_[(mt * 16 + quad * 4 + r) * 36 + o] = acc[r] + bi;  // D[m=px][n=o]
    }

    // ---- prefetch P4 B-fragments + b_out; loads stay in flight across P3 ----
    bf16x8 bfr4[4];
    float  bo4[4];
    #pragma unroll
    for (int ti = 0; ti < 4; ++ti) {
        int c = (wv * 4 + ti) * 16 + nn;
        bfr4[ti] = *(const bf16x8*)(w_out_bf + c * 32 + quad * 8);
        bo4[ti]  = b_out[c];
    }
    __syncthreads();

    // ---- P3 (ALL threads): circuits, perm-free (verified R8-R11) ----
    {
        int g = t >> 5, p = t & 31;
        float4 angv = *(const float4*)(as_ + p * 36 + g * 4);
        float angp[NDQ] = {angv.x, angv.y, angv.z, angv.w};

        v2f st2[32];
        #pragma unroll
        for (int k = 0; k < 32; ++k) st2[k] = (v2f){0.f, 0.f};
        st2[0].x = 1.f;

        #pragma unroll
        for (int l = 0; l < NLQ; ++l) {
            #pragma unroll
            for (int q = 0; q < NQB; ++q) {
                const int M = GT.M[l][q], V = GT.V[l][q];
                const int KD = M >> 1, SW = M & 1;
                int hh = KD; hh |= hh >> 1; hh |= hh >> 2; hh |= hh >> 4;
                const int HB = hh - (hh >> 1);
                float a = Ar[l * NQB + q] + (q < NDQ ? angp[q] : 0.f);
                float sn, cs;
                __sincosf(0.5f * a, &sn, &cs);
                v2f cs2 = {cs, cs};
                v2f sPP = {sn, sn}, sPM = {sn, -sn}, sMP = {-sn, sn}, sMM = {-sn, -sn};
                auto COV = [&](int i0) -> v2f {
                    bool p0 = parity6(i0 & V), p1 = parity6((i0 + 1) & V);
                    return p0 ? (p1 ? sPP : sPM) : (p1 ? sMP : sMM);
                };
                if (KD == 0) {
                    #pragma unroll
                    for (int k = 0; k < 32; ++k) {
                        v2f ov = __builtin_shufflevector(st2[k], st2[k], 1, 0);
                        st2[k] = __builtin_elementwise_fma(COV(2*k), ov, cs2 * st2[k]);
                    }
                } else {
                    #pragma unroll
                    for (int k = 0; k < 32; ++k) {
                        if (k & HB) continue;
                        int kp = k ^ KD;
                        v2f av = st2[k], bv = st2[kp];
                        v2f am = SW ? __builtin_shufflevector(av, av, 1, 0) : av;
                        v2f bm = SW ? __builtin_shufflevector(bv, bv, 1, 0) : bv;
                        st2[k]  = __builtin_elementwise_fma(COV(2*k),  bm, cs2 * av);
                        st2[kp] = __builtin_elementwise_fma(COV(2*kp), am, cs2 * bv);
                    }
                }
            }
        }

        #pragma unroll
        for (int k = 0; k < 32; ++k) st2[k] = st2[k] * st2[k];
        float md[NDQ];
        #pragma unroll
        for (int d = 0; d < NDQ; ++d) {
            const int W = GT.W[d];
            v2f acc = {0.f, 0.f};
            #pragma unroll
            for (int k = 0; k < 32; ++k) {
                v2f sg = { parity6((2*k)     & W) ? -1.f : 1.f,
                           parity6((2*k + 1) & W) ? -1.f : 1.f };
                acc = __builtin_elementwise_fma(sg, st2[k], acc);
            }
            md[d] = acc.x + acc.y;
        }
        float4 mv = {md[0], md[1], md[2], md[3]};
        *(float4*)(as_ + p * 36 + g * 4) = mv;   // meas overwrites own ang slot
    }
    __syncthreads();

    // ---- P4 (all waves): out = meas @ w_out^T + b_out + x, 2 px-tiles ----
    #pragma unroll
    for (int pt = 0; pt < 2; ++pt) {
        float4 m0 = *(const float4*)(as_ + (pt * 16 + nn) * 36 + quad * 8);
        float4 m1 = *(const float4*)(as_ + (pt * 16 + nn) * 36 + quad * 8 + 4);
        bf16x8 afr = { f2bf(m0.x), f2bf(m0.y), f2bf(m0.z), f2bf(m0.w),
                       f2bf(m1.x), f2bf(m1.y), f2bf(m1.z), f2bf(m1.w) };
        #pragma unroll
        for (int ti = 0; ti < 4; ++ti) {
            int c = (wv * 4 + ti) * 16 + nn;
            f32x4 acc = {0.f, 0.f, 0.f, 0.f};
            acc = __builtin_amdgcn_mfma_f32_16x16x32_bf16(afr, bfr4[ti], acc, 0, 0, 0);
            float4 x4 = *(const float4*)(xs2 + c * XSS + pt * 16 + quad * 4);
            float4 r;
            r.x = acc[0] + bo4[ti] + x4.x;
            r.y = acc[1] + bo4[ti] + x4.y;
            r.z = acc[2] + bo4[ti] + x4.z;
            r.w = acc[3] + bo4[ti] + x4.w;
            *(float4*)(out + (size_t)(b * NC + c) * NHW + pbase + pt * 16 + quad * 4) = r;
        }
    }
}

// ---------- fused cooperative kernel: grid = 512 x 256 (exactly 2/CU) ----------
// P0 (own x tile) issues BEFORE phase A so its HBM latency hides under the
// stats pass; grid.sync() replaces the k_pre->k_main kernel boundary.
__global__ __launch_bounds__(256, 2) void k_fused(
    const float* __restrict__ x,
    const float* __restrict__ emb,
    const float* __restrict__ w_style,
    const float* __restrict__ b_style,
    const float* __restrict__ theta,
    const float* __restrict__ w_in,
    const float* __restrict__ w_out,
    const float* __restrict__ gamma,
    const float* __restrict__ beta,
    const float* __restrict__ b_in,
    const float* __restrict__ b_out,
    float* __restrict__ ws,
    float* __restrict__ out) {

    __shared__ Smem sm;
    float* scs = ws;                    // [16][256]
    float* shs = ws + 4096;             // [16][256]
    float* A   = ws + 8192;             // [16][192]
    short* wbf = (short*)(ws + 12288);  // 16384 bf16: w_in | w_out

    int blk = blockIdx.x;               // 0..511: doubles as bg (stats) and tile id
    int t = threadIdx.x;
    int b = blk >> 5;
    int pbase = (blk & 31) * PIX;

    // ---- P0 first: own x tile -> regs + xs2 stash (overlaps phase A) ----
    float4 xr[8];
    {
        int c0 = t >> 3, p4 = (t & 7) * 4;
        #pragma unroll
        for (int k = 0; k < 8; ++k) {
            int c = c0 + 32 * k;
            xr[k] = *(const float4*)(x + (size_t)(b * NC + c) * NHW + pbase + p4);
            *(float4*)(sm.xs2 + c * XSS + p4) = xr[k];
        }
    }

    // ---- Phase A: stats for bg = blk (all 512 blocks) ----
    {
        const float4* xp = (const float4*)(x + (size_t)blk * 8 * NHW);
        float s = 0.f, ss = 0.f;
        for (int i = t; i < 8 * NHW / 4; i += 256) {
            float4 v = xp[i];
            s  += v.x + v.y + v.z + v.w;
            ss += v.x*v.x + v.y*v.y + v.z*v.z + v.w*v.w;
        }
        __shared__ float red0[4], red1[4];
        #pragma unroll
        for (int o = 32; o; o >>= 1) { s += __shfl_down(s, o); ss += __shfl_down(ss, o); }
        int lane = t & 63, w = t >> 6;
        if (lane == 0) { red0[w] = s; red1[w] = ss; }
        __syncthreads();
        if (t == 0) {
            s  = red0[0] + red0[1] + red0[2] + red0[3];
            ss = red1[0] + red1[1] + red1[2] + red1[3];
            float m = s * (1.f / 8192.f);
            float rsv = rsqrtf(ss * (1.f / 8192.f) - m * m + 1e-5f);
            int cbase = (blk & 31) * 8;
            #pragma unroll
            for (int j = 0; j < 8; ++j) {
                int c = cbase + j;
                float sc = rsv * gamma[c];
                scs[b * NC + c] = sc;
                shs[b * NC + c] = fmaf(-m, sc, beta[c]);
            }
        }

        // ---- style: spread over blocks 0..127 (b = blk>>3, 24 outputs each) ----
        if (blk < 128) {
            int sb = blk >> 3, part = blk & 7;
            float* es = sm.as_;             // alias: as_ unused until P2
            for (int i = t; i < NE; i += 256) {
                float v = emb[sb * NE + i];
                es[i] = v / (1.f + __expf(-v));
            }
            __syncthreads();
            int j0 = t >> 3, sub = t & 7;
            if (j0 < 24) {
                int j = part * 24 + j0;
                const float* wr = w_style + (size_t)j * NE + sub * 64;
                const float* er = es + sub * 64;
                float acc = 0.f;
                #pragma unroll
                for (int i = 0; i < 64; i += 4) {
                    float4 w4 = *(const float4*)(wr + i);
                    acc = fmaf(w4.x, er[i],   acc);
                    acc = fmaf(w4.y, er[i+1], acc);
                    acc = fmaf(w4.z, er[i+2], acc);
                    acc = fmaf(w4.w, er[i+3], acc);
                }
                acc += __shfl_xor(acc, 1);
                acc += __shfl_xor(acc, 2);
                acc += __shfl_xor(acc, 4);
                if (sub == 0) A[sb * 192 + j] = theta[j] + b_style[j] + acc;
            }
        } else if (blk < 144) {
            // ---- weight cvt: blocks 128..143, 512 w_in + 512 w_out each ----
            int kk = blk - 128;
            for (int i = t; i < 512; i += 256) {
                wbf[kk * 512 + i]        = f2bf(w_in[kk * 512 + i]);
                wbf[8192 + kk * 512 + i] = f2bf(w_out[kk * 512 + i]);
            }
        }
    }

    cooperative_groups::this_grid().sync();

    phaseB(sm, xr, b, pbase, t, scs, shs, b_in, A, wbf, wbf + 8192, b_out, out);
}

// ---------- fallback path (proven R3 structure), used if cooperative launch fails ----------
__global__ __launch_bounds__(256) void k_pre(const float* __restrict__ x,
                                             const float* __restrict__ emb,
                                             const float* __restrict__ w_style,
                                             const float* __restrict__ b_style,
                                             const float* __restrict__ theta,
                                             const float* __restrict__ w_in,
                                             const float* __restrict__ w_out,
                                             const float* __restrict__ gamma,
                                             const float* __restrict__ beta,
                                             float* __restrict__ scs,
                                             float* __restrict__ shs,
                                             float* __restrict__ A,
                                             short* __restrict__ wbf) {
    if (blockIdx.x < 512) {
        int bg = blockIdx.x;
        const float4* xp = (const float4*)(x + (size_t)bg * 8 * NHW);
        float s = 0.f, ss = 0.f;
        for (int i = threadIdx.x; i < 8 * NHW / 4; i += 256) {
            float4 v = xp[i];
            s  += v.x + v.y + v.z + v.w;
            ss += v.x*v.x + v.y*v.y + v.z*v.z + v.w*v.w;
        }
        __shared__ float red0[4], red1[4];
        #pragma unroll
        for (int o = 32; o; o >>= 1) { s += __shfl_down(s, o); ss += __shfl_down(ss, o); }
        int lane = threadIdx.x & 63, w = threadIdx.x >> 6;
        if (lane == 0) { red0[w] = s; red1[w] = ss; }
        __syncthreads();
        if (threadIdx.x == 0) {
            s  = red0[0] + red0[1] + red0[2] + red0[3];
            ss = red1[0] + red1[1] + red1[2] + red1[3];
            float m = s * (1.f / 8192.f);
            float rsv = rsqrtf(ss * (1.f / 8192.f) - m * m + 1e-5f);
            int cbase = (bg & 31) * 8;
            int b = bg >> 5;
            #pragma unroll
            for (int j = 0; j < 8; ++j) {
                int c = cbase + j;
                float sc = rsv * gamma[c];
                scs[b * NC + c] = sc;
                shs[b * NC + c] = fmaf(-m, sc, beta[c]);
            }
        }
    } else if (blockIdx.x < 512 + NB) {
        int b = blockIdx.x - 512;
        __shared__ float es[NE];
        int t = threadIdx.x;
        for (int i = t; i < NE; i += 256) {
            float v = emb[b * NE + i];
            es[i] = v / (1.f + __expf(-v));
        }
        __syncthreads();
        int j0 = t >> 3, sub = t & 7;
        for (int pass = 0; pass < 6; ++pass) {
            int j = pass * 32 + j0;
            const float* wr = w_style + (size_t)j * NE + sub * 64;
            const float* er = es + sub * 64;
            float acc = 0.f;
            #pragma unroll
            for (int i = 0; i < 64; i += 4) {
                float4 w4 = *(const float4*)(wr + i);
                acc = fmaf(w4.x, er[i],   acc);
                acc = fmaf(w4.y, er[i+1], acc);
                acc = fmaf(w4.z, er[i+2], acc);
                acc = fmaf(w4.w, er[i+3], acc);
            }
            acc += __shfl_xor(acc, 1);
            acc += __shfl_xor(acc, 2);
            acc += __shfl_xor(acc, 4);
            if (sub == 0) A[b * 192 + j] = theta[j] + b_style[j] + acc;
        }
    } else {
        for (int i = threadIdx.x; i < 8192; i += 256) wbf[i] = f2bf(w_in[i]);
        for (int i = threadIdx.x; i < 8192; i += 256) wbf[8192 + i] = f2bf(w_out[i]);
    }
}

__global__ __launch_bounds__(256, 2) void k_main_fb(
    const float* __restrict__ x,
    const float* __restrict__ scs,
    const float* __restrict__ shs,
    const float* __restrict__ b_in,
    const float* __restrict__ A,
    const short* __restrict__ w_in_bf,
    const short* __restrict__ w_out_bf,
    const float* __restrict__ b_out,
    float* __restrict__ out) {

    __shared__ Smem sm;
    int blk = blockIdx.x, t = threadIdx.x;
    int b = blk >> 5;
    int pbase = (blk & 31) * PIX;

    float4 xr[8];
    {
        int c0 = t >> 3, p4 = (t & 7) * 4;
        #pragma unroll
        for (int k = 0; k < 8; ++k) {
            int c = c0 + 32 * k;
            xr[k] = *(const float4*)(x + (size_t)(b * NC + c) * NHW + pbase + p4);
            *(float4*)(sm.xs2 + c * XSS + p4) = xr[k];
        }
    }
    phaseB(sm, xr, b, pbase, t, scs, shs, b_in, A, w_in_bf, w_out_bf, b_out, out);
}

extern "C" void kernel_launch(void* const* d_in, const int* in_sizes, int n_in,
                              void* d_out, int out_size, void* d_ws, size_t ws_size,
                              hipStream_t stream) {
    const float* x       = (const float*)d_in[0];
    const float* emb     = (const float*)d_in[1];
    const float* gamma   = (const float*)d_in[2];
    const float* beta    = (const float*)d_in[3];
    const float* w_in    = (const float*)d_in[4];
    const float* b_in    = (const float*)d_in[5];
    const float* theta   = (const float*)d_in[6];
    const float* w_style = (const float*)d_in[7];
    const float* b_style = (const float*)d_in[8];
    const float* w_out   = (const float*)d_in[9];
    const float* b_out   = (const float*)d_in[10];
    float* out = (float*)d_out;

    float* ws  = (float*)d_ws;
    float* scs = ws;                        // 4096
    float* shs = ws + 4096;                 // 4096
    float* A   = ws + 8192;                 // 3072
    short* wbf = (short*)(ws + 12288);      // 16384 bf16: w_in | w_out

    // cooperative fused path
    const float* x_ = x;  const float* emb_ = emb;  const float* wst_ = w_style;
    const float* bst_ = b_style;  const float* th_ = theta;  const float* wi_ = w_in;
    const float* wo_ = w_out;  const float* ga_ = gamma;  const float* be_ = beta;
    const float* bi_ = b_in;  const float* bo_ = b_out;
    float* ws_ = ws;  float* out_ = out;
    void* args[] = { &x_, &emb_, &wst_, &bst_, &th_, &wi_, &wo_, &ga_, &be_,
                     &bi_, &bo_, &ws_, &out_ };
    hipError_t e = hipLaunchCooperativeKernel((void*)k_fused, dim3(512), dim3(256),
                                              args, 0, stream);
    if (e != hipSuccess) {
        (void)hipGetLastError();   // clear sticky error; fall back to two-kernel path
        k_pre<<<512 + NB + 1, 256, 0, stream>>>(x, emb, w_style, b_style, theta,
                                                w_in, w_out, gamma, beta,
                                                scs, shs, A, wbf);
        k_main_fb<<<NB * 32, 256, 0, stream>>>(x, scs, shs, b_in, A,
                                               wbf, wbf + 8192, b_out, out);
    }
}

// Round 6
// 118.444 us; speedup vs baseline: 1.6147x; 1.6147x over previous
//
#include <hip/hip_runtime.h>
#include <math.h>

#define NB 16
#define NC 256
#define NHW 1024
#define NE 512
#define NDQ 4
#define NLQ 4
#define NQB 6
#define QDIM 64
#define PIX 32
#define HSS 264    // hs row stride in bf16 elems (2-way bank conflict = free)
#define XSS 36     // xs2 row stride (floats): 32->36 kills 16-way P4 read conflict

typedef float v2f __attribute__((ext_vector_type(2)));
typedef float f32x4 __attribute__((ext_vector_type(4)));
typedef short bf16x8 __attribute__((ext_vector_type(8)));   // 8 bf16 (4 VGPRs)

__device__ __forceinline__ short f2bf(float v) {   // RNE f32 -> bf16 bits
    unsigned u = __builtin_bit_cast(unsigned, v);
    u += 0x7FFFu + ((u >> 16) & 1u);
    return (short)(u >> 16);
}

// ======== constexpr circuit algebra (CNOT ring is GF(2)-linear) ========
constexpr int fwd1(int i) {
    int r = i;
    for (int c = 0; c < NQB; ++c) {
        int t = (c + 1) % NQB;
        if ((r >> (NQB - 1 - c)) & 1) r ^= 1 << (NQB - 1 - t);
    }
    return r;
}
constexpr int fwdl(int s, int l) { for (int i = 0; i < l; ++i) s = fwd1(s); return s; }
constexpr int parity6(int x) { x ^= x >> 4; x ^= x >> 2; x ^= x >> 1; return x & 1; }

// Verified by R8-R11 passing runs.
struct GateTab { int M[NLQ][NQB]; int V[NLQ][NQB]; int W[NDQ]; };
constexpr GateTab make_tab() {
    GateTab g{};
    for (int l = 0; l < NLQ; ++l)
        for (int q = 0; q < NQB; ++q) {
            int m = 1 << (NQB - 1 - q);
            for (int x = 0; x < QDIM; ++x) if (fwdl(x, l) == m) { g.M[l][q] = x; break; }
            int V = 0;
            for (int t = 0; t < NQB; ++t) V |= ((fwdl(1 << t, l) >> (NQB - 1 - q)) & 1) << t;
            g.V[l][q] = V;
        }
    for (int d = 0; d < NDQ; ++d) {
        int W = 0;
        for (int t = 0; t < NQB; ++t) W |= ((fwdl(1 << t, NLQ) >> (NQB - 1 - d)) & 1) << t;
        g.W[d] = W;
    }
    return g;
}
constexpr GateTab GT = make_tab();

// ---- Kernel 1: stats->scale/shift (blk<512) + style (512..527) + w cvt (528) ----
__global__ __launch_bounds__(256) void k_pre(const float* __restrict__ x,
                                             const float* __restrict__ emb,
                                             const float* __restrict__ w_style,
                                             const float* __restrict__ b_style,
                                             const float* __restrict__ theta,
                                             const float* __restrict__ w_in,
                                             const float* __restrict__ w_out,
                                             const float* __restrict__ gamma,
                                             const float* __restrict__ beta,
                                             float* __restrict__ scs,
                                             float* __restrict__ shs,
                                             float* __restrict__ A,
                                             short* __restrict__ wbf) {
    if (blockIdx.x < 512) {
        int bg = blockIdx.x;                 // b*32 + g
        const float4* xp = (const float4*)(x + (size_t)bg * 8 * NHW);
        float s = 0.f, ss = 0.f;
        for (int i = threadIdx.x; i < 8 * NHW / 4; i += 256) {
            float4 v = xp[i];
            s  += v.x + v.y + v.z + v.w;
            ss += v.x*v.x + v.y*v.y + v.z*v.z + v.w*v.w;
        }
        __shared__ float red0[4], red1[4];
        #pragma unroll
        for (int o = 32; o; o >>= 1) { s += __shfl_down(s, o); ss += __shfl_down(ss, o); }
        int lane = threadIdx.x & 63, w = threadIdx.x >> 6;
        if (lane == 0) { red0[w] = s; red1[w] = ss; }
        __syncthreads();
        if (threadIdx.x == 0) {
            s  = red0[0] + red0[1] + red0[2] + red0[3];
            ss = red1[0] + red1[1] + red1[2] + red1[3];
            float m = s * (1.f / 8192.f);
            float rsv = rsqrtf(ss * (1.f / 8192.f) - m * m + 1e-5f);
            int cbase = (bg & 31) * 8;       // channels of this group
            int b = bg >> 5;
            #pragma unroll
            for (int j = 0; j < 8; ++j) {
                int c = cbase + j;
                float sc = rsv * gamma[c];
                scs[b * NC + c] = sc;
                shs[b * NC + c] = fmaf(-m, sc, beta[c]);
            }
        }
    } else if (blockIdx.x < 512 + NB) {
        int b = blockIdx.x - 512;
        __shared__ float es[NE];
        int t = threadIdx.x;
        for (int i = t; i < NE; i += 256) {
            float v = emb[b * NE + i];
            es[i] = v / (1.f + __expf(-v));
        }
        __syncthreads();
        int j0 = t >> 3, sub = t & 7;
        for (int pass = 0; pass < 6; ++pass) {
            int j = pass * 32 + j0;
            const float* wr = w_style + (size_t)j * NE + sub * 64;
            const float* er = es + sub * 64;
            float acc = 0.f;
            #pragma unroll
            for (int i = 0; i < 64; i += 4) {
                float4 w4 = *(const float4*)(wr + i);
                acc = fmaf(w4.x, er[i],   acc);
                acc = fmaf(w4.y, er[i+1], acc);
                acc = fmaf(w4.z, er[i+2], acc);
                acc = fmaf(w4.w, er[i+3], acc);
            }
            acc += __shfl_xor(acc, 1);
            acc += __shfl_xor(acc, 2);
            acc += __shfl_xor(acc, 4);
            if (sub == 0) A[b * 192 + j] = theta[j] + b_style[j] + acc;
        }
    } else {
        for (int i = threadIdx.x; i < 8192; i += 256) wbf[i] = f2bf(w_in[i]);
        for (int i = threadIdx.x; i < 8192; i += 256) wbf[8192 + i] = f2bf(w_out[i]);
    }
}

// ---- Kernel 2: symmetric all-wave schedule (R3-proven) + padded xs2 (R4 pad).
// grid = 512 x 256, PIX=32. All 4 waves work every phase.
__global__ __launch_bounds__(256, 2) void k_main(
    const float* __restrict__ x,
    const float* __restrict__ scs,
    const float* __restrict__ shs,
    const float* __restrict__ b_in,
    const float* __restrict__ A,
    const short* __restrict__ w_in_bf,    // [o][c] bf16, 32x256
    const short* __restrict__ w_out_bf,   // [c][o] bf16, 256x32
    const float* __restrict__ b_out,
    float* __restrict__ out) {

    __shared__ short hs[PIX * HSS];     // normalized h bf16 [px][c], 16.9 KB
    __shared__ float xs2[NC * XSS];     // raw x stash [c][px] padded, 36.9 KB
    __shared__ float as_[PIX * 36];     // ang/meas [px][o], 4.5 KB

    int blk = blockIdx.x;
    int b = blk >> 5;
    int pbase = (blk & 31) * PIX;
    int t = threadIdx.x;
    int lane = t & 63, wv = t >> 6;
    int c0 = t >> 3, p4 = (t & 7) * 4;   // P0/P1: 8 channels (c0+32k) x 4 pixels
    int nn = lane & 15, quad = lane >> 4;
    int mt = wv >> 1, nt = wv & 1;       // P2 tile: px-half, o-half

    // ---- P0: load x tile; stash raw immediately in [c][px] layout ----
    float4 xr[8];
    #pragma unroll
    for (int k = 0; k < 8; ++k) {
        int c = c0 + 32 * k;
        xr[k] = *(const float4*)(x + (size_t)(b * NC + c) * NHW + pbase + p4);
        *(float4*)(xs2 + c * XSS + p4) = xr[k];
    }

    // ---- all waves: preload own P2 B-fragments (w_in bf16) ----
    bf16x8 bfrag[8];
    {
        int o = nt * 16 + nn;
        #pragma unroll
        for (int s = 0; s < 8; ++s)
            bfrag[s] = *(const bf16x8*)(w_in_bf + o * NC + s * 32 + quad * 8);
    }

    // ---- all threads: preload style table (L2 latency hides under P1/P2) ----
    float Ar[24];
    {
        int g = t >> 5;
        const float4* Ab4 = (const float4*)(A + b * 192 + g * 24);
        #pragma unroll
        for (int j = 0; j < 6; ++j) {
            float4 a4 = Ab4[j];
            Ar[4*j] = a4.x; Ar[4*j+1] = a4.y; Ar[4*j+2] = a4.z; Ar[4*j+3] = a4.w;
        }
    }

    // ---- P1: normalize (precomputed scale/shift) -> hs bf16 [px][c] ----
    #pragma unroll
    for (int k = 0; k < 8; ++k) {
        int c = c0 + 32 * k;
        float sc = scs[b * NC + c];
        float sh = shs[b * NC + c];
        float4 v = xr[k];
        hs[(p4 + 0) * HSS + c] = f2bf(fmaf(v.x, sc, sh));
        hs[(p4 + 1) * HSS + c] = f2bf(fmaf(v.y, sc, sh));
        hs[(p4 + 2) * HSS + c] = f2bf(fmaf(v.z, sc, sh));
        hs[(p4 + 3) * HSS + c] = f2bf(fmaf(v.w, sc, sh));
    }
    __syncthreads();

    // ---- P2 (all waves): ang = h @ w_in^T via MFMA 16x16x32, one tile/wave ----
    {
        f32x4 acc = {0.f, 0.f, 0.f, 0.f};
        #pragma unroll
        for (int s = 0; s < 8; ++s) {
            bf16x8 afr = *(const bf16x8*)(hs + (mt * 16 + nn) * HSS + s * 32 + quad * 8);
            acc = __builtin_amdgcn_mfma_f32_16x16x32_bf16(afr, bfrag[s], acc, 0, 0, 0);
        }
        int o = nt * 16 + nn;
        float bi = b_in[o];
        #pragma unroll
        for (int r = 0; r < 4; ++r)
            as_[(mt * 16 + quad * 4 + r) * 36 + o] = acc[r] + bi;  // D[m=px][n=o]
    }

    // ---- ALL waves: prefetch P4 B-fragments + b_out; loads stay in flight
    //      across the P3 phase ----
    bf16x8 bfr4[4];
    float  bo4[4];
    #pragma unroll
    for (int ti = 0; ti < 4; ++ti) {
        int c = (wv * 4 + ti) * 16 + nn;
        bfr4[ti] = *(const bf16x8*)(w_out_bf + c * 32 + quad * 8);
        bo4[ti]  = b_out[c];
    }
    __syncthreads();

    // ---- P3 (ALL threads): circuits, perm-free (verified R8-R11) ----
    {
        int g = t >> 5, p = t & 31;
        float4 angv = *(const float4*)(as_ + p * 36 + g * 4);
        float angp[NDQ] = {angv.x, angv.y, angv.z, angv.w};

        v2f st2[32];
        #pragma unroll
        for (int k = 0; k < 32; ++k) st2[k] = (v2f){0.f, 0.f};
        st2[0].x = 1.f;

        #pragma unroll
        for (int l = 0; l < NLQ; ++l) {
            #pragma unroll
            for (int q = 0; q < NQB; ++q) {
                const int M = GT.M[l][q], V = GT.V[l][q];
                const int KD = M >> 1, SW = M & 1;
                int hh = KD; hh |= hh >> 1; hh |= hh >> 2; hh |= hh >> 4;
                const int HB = hh - (hh >> 1);
                float a = Ar[l * NQB + q] + (q < NDQ ? angp[q] : 0.f);
                float sn, cs;
                __sincosf(0.5f * a, &sn, &cs);
                v2f cs2 = {cs, cs};
                v2f sPP = {sn, sn}, sPM = {sn, -sn}, sMP = {-sn, sn}, sMM = {-sn, -sn};
                auto COV = [&](int i0) -> v2f {
                    bool p0 = parity6(i0 & V), p1 = parity6((i0 + 1) & V);
                    return p0 ? (p1 ? sPP : sPM) : (p1 ? sMP : sMM);
                };
                if (KD == 0) {
                    #pragma unroll
                    for (int k = 0; k < 32; ++k) {
                        v2f ov = __builtin_shufflevector(st2[k], st2[k], 1, 0);
                        st2[k] = __builtin_elementwise_fma(COV(2*k), ov, cs2 * st2[k]);
                    }
                } else {
                    #pragma unroll
                    for (int k = 0; k < 32; ++k) {
                        if (k & HB) continue;
                        int kp = k ^ KD;
                        v2f av = st2[k], bv = st2[kp];
                        v2f am = SW ? __builtin_shufflevector(av, av, 1, 0) : av;
                        v2f bm = SW ? __builtin_shufflevector(bv, bv, 1, 0) : bv;
                        st2[k]  = __builtin_elementwise_fma(COV(2*k),  bm, cs2 * av);
                        st2[kp] = __builtin_elementwise_fma(COV(2*kp), am, cs2 * bv);
                    }
                }
            }
        }

        #pragma unroll
        for (int k = 0; k < 32; ++k) st2[k] = st2[k] * st2[k];
        float md[NDQ];
        #pragma unroll
        for (int d = 0; d < NDQ; ++d) {
            const int W = GT.W[d];
            v2f acc = {0.f, 0.f};
            #pragma unroll
            for (int k = 0; k < 32; ++k) {
                v2f sg = { parity6((2*k)     & W) ? -1.f : 1.f,
                           parity6((2*k + 1) & W) ? -1.f : 1.f };
                acc = __builtin_elementwise_fma(sg, st2[k], acc);
            }
            md[d] = acc.x + acc.y;
        }
        float4 mv = {md[0], md[1], md[2], md[3]};
        *(float4*)(as_ + p * 36 + g * 4) = mv;   // meas overwrites own ang slot
    }
    __syncthreads();

    // ---- P4 (all waves): out = meas @ w_out^T + b_out + x, 2 px-tiles ----
    #pragma unroll
    for (int pt = 0; pt < 2; ++pt) {
        float4 m0 = *(const float4*)(as_ + (pt * 16 + nn) * 36 + quad * 8);
        float4 m1 = *(const float4*)(as_ + (pt * 16 + nn) * 36 + quad * 8 + 4);
        bf16x8 afr = { f2bf(m0.x), f2bf(m0.y), f2bf(m0.z), f2bf(m0.w),
                       f2bf(m1.x), f2bf(m1.y), f2bf(m1.z), f2bf(m1.w) };
        #pragma unroll
        for (int ti = 0; ti < 4; ++ti) {
            int c = (wv * 4 + ti) * 16 + nn;
            f32x4 acc = {0.f, 0.f, 0.f, 0.f};
            acc = __builtin_amdgcn_mfma_f32_16x16x32_bf16(afr, bfr4[ti], acc, 0, 0, 0);
            float4 x4 = *(const float4*)(xs2 + c * XSS + pt * 16 + quad * 4);
            float4 r;
            r.x = acc[0] + bo4[ti] + x4.x;
            r.y = acc[1] + bo4[ti] + x4.y;
            r.z = acc[2] + bo4[ti] + x4.z;
            r.w = acc[3] + bo4[ti] + x4.w;
            *(float4*)(out + (size_t)(b * NC + c) * NHW + pbase + pt * 16 + quad * 4) = r;
        }
    }
}

extern "C" void kernel_launch(void* const* d_in, const int* in_sizes, int n_in,
                              void* d_out, int out_size, void* d_ws, size_t ws_size,
                              hipStream_t stream) {
    const float* x       = (const float*)d_in[0];
    const float* emb     = (const float*)d_in[1];
    const float* gamma   = (const float*)d_in[2];
    const float* beta    = (const float*)d_in[3];
    const float* w_in    = (const float*)d_in[4];
    const float* b_in    = (const float*)d_in[5];
    const float* theta   = (const float*)d_in[6];
    const float* w_style = (const float*)d_in[7];
    const float* b_style = (const float*)d_in[8];
    const float* w_out   = (const float*)d_in[9];
    const float* b_out   = (const float*)d_in[10];
    float* out = (float*)d_out;

    float* ws  = (float*)d_ws;
    float* scs = ws;                        // 4096
    float* shs = ws + 4096;                 // 4096
    float* A   = ws + 8192;                 // 3072
    short* wbf = (short*)(ws + 12288);      // 16384 bf16: w_in | w_out

    k_pre<<<512 + NB + 1, 256, 0, stream>>>(x, emb, w_style, b_style, theta,
                                            w_in, w_out, gamma, beta,
                                            scs, shs, A, wbf);
    k_main<<<NB * 32, 256, 0, stream>>>(x, scs, shs, b_in, A,
                                        wbf, wbf + 8192, b_out, out);
}